// Round 6
// baseline (394.620 us; speedup 1.0000x reference)
//
#include <hip/hip_runtime.h>
#include <hip/hip_cooperative_groups.h>

namespace cg = cooperative_groups;

// MultiCenterLoss: loss = sum_{label==0} min_c ||f - c + eps||_2 / (count + 1e-5)
// ||f-c+eps||^2 = [f2 + 2*eps*fs + eps^2*D] + [c2 - 2*eps*cs] - 2*f.c
// min over c commutes with the per-sample constant. f.c via bf16 MFMA 16x16x32.
// Preferred path: ONE cooperative kernel (512 blocks, guaranteed co-resident via
// __launch_bounds__(256,2)). If the cooperative launch is refused, fall back to
// the same three phases as three ordinary kernels (stream order = sync).
// Cross-XCD rule: all cross-phase scalars move through device-scope atomics;
// only cent_bf (2KB-aligned rows, no false sharing, fenced) uses plain loads.

constexpr int N = 16384;
constexpr int D = 1024;
constexpr int C = 1024;
constexpr float EPS = 1e-6f;

constexpr int SB = 16;    // samples per work item
constexpr int CB = 128;   // centers per work item
constexpr int BK = 64;    // K elements per stage
constexpr int TPB = 256;
constexpr int COOP_GRID = 512;  // 2 blocks/CU x 256 CUs — always fits

typedef __attribute__((ext_vector_type(8))) short bf16x8;
typedef __attribute__((ext_vector_type(4))) float f32x4;

struct Ctx {
  const float* feat;
  const int* labels;
  const float* cent;
  unsigned* count;
  float* num;
  unsigned* done;
  unsigned* minmapped;
  unsigned* sel;
  float* cc;
  unsigned short* cent_bf;
  float* out;
};

// order-preserving float<->uint map (finite floats)
__device__ inline unsigned mapf(float f) {
  unsigned b = __float_as_uint(f);
  return (b & 0x80000000u) ? ~b : (b | 0x80000000u);
}
__device__ inline float unmapf(unsigned u) {
  return __uint_as_float((u & 0x80000000u) ? (u ^ 0x80000000u) : ~u);
}

// fp32 -> bf16 bits, round-to-nearest-even (inputs finite)
__device__ inline unsigned short f2bf(float x) {
  unsigned u = __float_as_uint(x);
  return (unsigned short)((u + 0x7FFFu + ((u >> 16) & 1u)) >> 16);
}

#define GLOAD_LDS16(gp, lp)                                        \
  __builtin_amdgcn_global_load_lds(                                \
      (const __attribute__((address_space(1))) void*)(gp),         \
      (__attribute__((address_space(3))) void*)(lp), 16, 0, 0)

// ---- Phase A: minmapped init + label==0 gather + bf16 convert + cc ----
__device__ void phase_init(const Ctx& c, float* red, int b, int gs) {
  const int t = threadIdx.x;
  const int lane = t & 63, w = t >> 6;
  for (int n = b * TPB + t; n < N; n += gs * TPB) {
    atomicExch(&c.minmapped[n], 0xFFFFFFFFu);
    if (c.labels[n] == 0) {
      unsigned slot = atomicAdd(c.count, 1u);
      atomicExch(&c.sel[slot], (unsigned)n);
    }
  }
  for (int r = b; r < C; r += gs) {
    const float* row = c.cent + (size_t)r * D;
    float4 v = *(const float4*)(row + t * 4);
    *(short4*)(c.cent_bf + (size_t)r * D + t * 4) =
        make_short4((short)f2bf(v.x), (short)f2bf(v.y), (short)f2bf(v.z),
                    (short)f2bf(v.w));
    float s1 = v.x + v.y + v.z + v.w;
    float s2 = v.x * v.x + v.y * v.y + v.z * v.z + v.w * v.w;
#pragma unroll
    for (int off = 32; off; off >>= 1) {
      s1 += __shfl_down(s1, off);
      s2 += __shfl_down(s2, off);
    }
    if (lane == 0) { red[w] = s1; red[4 + w] = s2; }
    __syncthreads();
    if (t == 0) {
      float a1 = red[0] + red[1] + red[2] + red[3];
      float a2 = red[4] + red[5] + red[6] + red[7];
      atomicExch(&c.cc[r], a2 - 2.0f * EPS * a1);
    }
    __syncthreads();
  }
}

// ---- Phase C: minmapped[s] = min_c (cc[c] - 2*f.c) via bf16 MFMA ----
__device__ void phase_dist(const Ctx& c, unsigned short* Cb, unsigned short* Fb,
                           unsigned* rows_s, unsigned* cnt_p, int b, int gs) {
  const int t = threadIdx.x;
  const int lane = t & 63, w = t >> 6;
  if (t == 0) *cnt_p = atomicAdd(c.count, 0u);
  __syncthreads();
  const unsigned cnt = *cnt_p;
  const unsigned nwork = ((cnt + SB - 1) / SB) * (C / CB);

  // F staging geometry: thread t -> sample s = t>>4, k4 = (t&15)*4
  const int fs_ = t >> 4;
  const int fk4 = (t & 15) * 4;
  const int fj = fk4 >> 3, fhalf = (fk4 >> 2) & 1;
  const int foff = fs_ * BK + ((fj ^ (fs_ & 7)) << 3) + (fhalf << 2);
  const int arow = lane & 15, kg = lane >> 4;
  const int c0 = w * 32 + (lane & 15), c1 = c0 + 16;

  for (unsigned wk = (unsigned)b; wk < nwork; wk += (unsigned)gs) {
    const unsigned sbase = (wk >> 3) * SB;
    const unsigned cbase = (wk & 7) * CB;

    if (t < SB)
      rows_s[t] = atomicAdd(&c.sel[min(sbase + (unsigned)t, cnt - 1u)], 0u);
    __syncthreads();

    const float* fsrc = c.feat + (size_t)rows_s[fs_] * D + fk4;
    f32x4 acc0 = {0.f, 0.f, 0.f, 0.f}, acc1 = {0.f, 0.f, 0.f, 0.f};

    for (int kt = 0; kt < D / BK; ++kt) {
      const int kbase = kt * BK;
      // C tile: 1024 16B chunks, 4/thread; linear LDS dest,
      // inverse-swizzled global source (swizzle: 16B chunk j ^= row&7)
#pragma unroll
      for (int u = 0; u < 4; ++u) {
        int chunk = (w * 4 + u) * 64 + lane;
        int r = chunk >> 3, j = chunk & 7;
        int jsrc = j ^ (r & 7);
        const unsigned short* src =
            c.cent_bf + (size_t)(cbase + r) * D + kbase + jsrc * 8;
        GLOAD_LDS16(src, Cb + chunk * 8);
      }
      // F tile: one float4/thread, convert, swizzled ds_write
      {
        float4 v = *(const float4*)(fsrc + kbase);
        *(short4*)(Fb + foff) = make_short4((short)f2bf(v.x), (short)f2bf(v.y),
                                            (short)f2bf(v.z), (short)f2bf(v.w));
      }
      __syncthreads();

#pragma unroll
      for (int ks = 0; ks < 2; ++ks) {
        int jj = (ks << 2) + kg;
        bf16x8 a = *(const bf16x8*)(Fb + arow * BK + ((jj ^ (arow & 7)) << 3));
        bf16x8 b0 = *(const bf16x8*)(Cb + c0 * BK + ((jj ^ (c0 & 7)) << 3));
        bf16x8 b1 = *(const bf16x8*)(Cb + c1 * BK + ((jj ^ (c1 & 7)) << 3));
        acc0 = __builtin_amdgcn_mfma_f32_16x16x32_bf16(a, b0, acc0, 0, 0, 0);
        acc1 = __builtin_amdgcn_mfma_f32_16x16x32_bf16(a, b1, acc1, 0, 0, 0);
      }
      __syncthreads();
    }

    // epilogue: cand = cc[c] - 2*dot; C/D layout: col=lane&15, row=(lane>>4)*4+reg
    float ccv0 = atomicAdd(&c.cc[cbase + c0], 0.0f);
    float ccv1 = atomicAdd(&c.cc[cbase + c1], 0.0f);
#pragma unroll
    for (int reg = 0; reg < 4; ++reg) {
      float v = fminf(ccv0 - 2.0f * acc0[reg], ccv1 - 2.0f * acc1[reg]);
#pragma unroll
      for (int off = 1; off < 16; off <<= 1) v = fminf(v, __shfl_xor(v, off));
      if ((lane & 15) == 0) {
        unsigned sidx = sbase + (unsigned)((lane >> 4) * 4 + reg);
        if (sidx < cnt) atomicMin(&c.minmapped[sidx], mapf(v));
      }
    }
    __syncthreads();  // protect rows_s/tiles before next work item
  }
}

// ---- Phase D: per-sample constant + sqrt + sum; last block writes out ----
__device__ void phase_reduce(const Ctx& c, unsigned* cnt_p, int b, int gs,
                             unsigned nblocks) {
  const int t = threadIdx.x;
  const int lane = t & 63, w = t >> 6;
  if (t == 0) *cnt_p = atomicAdd(c.count, 0u);
  __syncthreads();
  const unsigned cnt = *cnt_p;

  for (unsigned slot = (unsigned)(b * 4 + w); slot < cnt;
       slot += (unsigned)gs * 4) {
    unsigned srow = 0;
    if (lane == 0) srow = atomicAdd(&c.sel[slot], 0u);
    srow = __shfl(srow, 0);
    const float* row = c.feat + (size_t)srow * D;
    float s1 = 0.f, s2 = 0.f;
#pragma unroll
    for (int j = 0; j < D / 64; ++j) {
      float v = row[lane + 64 * j];
      s1 += v;
      s2 += v * v;
    }
#pragma unroll
    for (int off = 32; off; off >>= 1) {
      s1 += __shfl_down(s1, off);
      s2 += __shfl_down(s2, off);
    }
    if (lane == 0) {
      float ff = s2 + 2.0f * EPS * s1 + EPS * EPS * (float)D;
      float sq = ff + unmapf(atomicAdd(&c.minmapped[slot], 0u));
      atomicAdd(c.num, sqrtf(fmaxf(sq, 0.0f)));
    }
  }
  __syncthreads();
  if (t == 0) {
    __threadfence();
    unsigned v = atomicAdd(c.done, 1u);
    if (v == nblocks - 1u) {
      float total = atomicAdd(c.num, 0.0f);  // coherence-point read
      c.out[0] = total / ((float)cnt + 1e-5f);
    }
  }
}

struct ShmAll {
  unsigned short Cb[CB * BK];  // 16 KB
  unsigned short Fb[SB * BK];  // 2 KB
  unsigned rows[SB];
  float red[8];
  unsigned cnt;
};

__global__ __launch_bounds__(TPB, 2) void k_all(Ctx c) {
  __shared__ __align__(16) ShmAll sh;
  cg::grid_group g = cg::this_grid();
  const int b = blockIdx.x, gs = gridDim.x;
  phase_init(c, sh.red, b, gs);
  __threadfence();
  g.sync();
  phase_dist(c, sh.Cb, sh.Fb, sh.rows, &sh.cnt, b, gs);
  __threadfence();
  g.sync();
  phase_reduce(c, &sh.cnt, b, gs, (unsigned)gs);
}

// ---- fallback path: same phases, ordinary launches (stream order = sync) ----
__global__ __launch_bounds__(TPB) void k_init(Ctx c) {
  __shared__ float red[8];
  phase_init(c, red, blockIdx.x, gridDim.x);
}
__global__ __launch_bounds__(TPB) void k_dist2(Ctx c) {
  __shared__ __align__(16) unsigned short Cb[CB * BK];
  __shared__ __align__(16) unsigned short Fb[SB * BK];
  __shared__ unsigned rows[SB];
  __shared__ unsigned cnt;
  phase_dist(c, Cb, Fb, rows, &cnt, blockIdx.x, gridDim.x);
}
__global__ __launch_bounds__(TPB) void k_red(Ctx c) {
  __shared__ unsigned cnt;
  phase_reduce(c, &cnt, blockIdx.x, gridDim.x, (unsigned)gridDim.x);
}

extern "C" void kernel_launch(void* const* d_in, const int* in_sizes, int n_in,
                              void* d_out, int out_size, void* d_ws, size_t ws_size,
                              hipStream_t stream) {
  char* ws = (char*)d_ws;
  Ctx c;
  c.feat = (const float*)d_in[0];
  c.labels = (const int*)d_in[1];
  c.cent = (const float*)d_in[2];
  c.out = (float*)d_out;
  c.count = (unsigned*)ws;                                  // @0
  c.num = (float*)(ws + 4);                                 // @4
  c.done = (unsigned*)(ws + 8);                             // @8
  c.minmapped = (unsigned*)(ws + 16);                       // N u32
  c.sel = (unsigned*)(ws + 16 + 4 * (size_t)N);             // N u32
  c.cc = (float*)(ws + 16 + 8 * (size_t)N);                 // C f32
  c.cent_bf =
      (unsigned short*)(ws + 16 + 8 * (size_t)N + 4 * (size_t)C);  // C*D bf16

  hipMemsetAsync(d_ws, 0, 16, stream);

  void* args[] = {(void*)&c};
  hipError_t e = hipLaunchCooperativeKernel((void*)k_all, dim3(COOP_GRID),
                                            dim3(TPB), args, 0, stream);
  if (e != hipSuccess) {
    // same work, ordinary launches; kernel boundaries provide the grid syncs
    k_init<<<1024, TPB, 0, stream>>>(c);
    k_dist2<<<1024, TPB, 0, stream>>>(c);
    k_red<<<256, TPB, 0, stream>>>(c);
  }
}

// Round 7
// 140.148 us; speedup vs baseline: 2.8157x; 2.8157x over previous
//
#include <hip/hip_runtime.h>

// MultiCenterLoss: loss = sum_{label==0} min_c ||f - c + eps||_2 / (count + 1e-5)
// ||f-c+eps||^2 = [f2 + 2*eps*fs + eps^2*D] + [c2 - 2*eps*cs] - 2*f.c
// min over c commutes with the per-sample constant, so k_dist only needs
// min_c (cc[c] - 2*f.c); per-sample constant ff precomputed in k_setup.
// f.c via bf16 MFMA 16x16x32. Stream-ordered kernels; boundaries = grid sync
// (cooperative grid.sync measured 10x slower: cross-XCD spin, round 6).

constexpr int N = 16384;
constexpr int D = 1024;
constexpr int C = 1024;
constexpr float EPS = 1e-6f;

constexpr int SB = 16;    // samples per work item
constexpr int CB = 128;   // centers per work item
constexpr int BK = 64;    // K elements per stage
constexpr int TPB = 256;
constexpr int DIST_GRID = 1024;

typedef __attribute__((ext_vector_type(8))) short bf16x8;
typedef __attribute__((ext_vector_type(4))) float f32x4;

// order-preserving float<->uint map (finite floats)
__device__ inline unsigned mapf(float f) {
  unsigned b = __float_as_uint(f);
  return (b & 0x80000000u) ? ~b : (b | 0x80000000u);
}
__device__ inline float unmapf(unsigned u) {
  return __uint_as_float((u & 0x80000000u) ? (u ^ 0x80000000u) : ~u);
}

// fp32 -> bf16 bits, round-to-nearest-even (inputs finite)
__device__ inline unsigned short f2bf(float x) {
  unsigned u = __float_as_uint(x);
  return (unsigned short)((u + 0x7FFFu + ((u >> 16) & 1u)) >> 16);
}

#define GLOAD_LDS16(gp, lp)                                        \
  __builtin_amdgcn_global_load_lds(                                \
      (const __attribute__((address_space(1))) void*)(gp),         \
      (__attribute__((address_space(3))) void*)(lp), 16, 0, 0)

// ---- k_setup (1024 blocks): block b owns center row b and samples [16b,16b+16)
//   * minmapped init + label==0 gather
//   * center row b: fp32 -> bf16 + cc[b] = sum(c^2) - 2*eps*sum(c)
//   * ff[slot] = sum(f^2) + 2*eps*sum(f) + eps^2*D for this block's selected rows
__global__ __launch_bounds__(TPB) void k_setup(
    const float* __restrict__ feat, const int* __restrict__ labels,
    const float* __restrict__ cent, unsigned* __restrict__ count,
    unsigned* __restrict__ sel, unsigned* __restrict__ minmapped,
    float* __restrict__ cc, float* __restrict__ ff,
    unsigned short* __restrict__ cent_bf) {
  __shared__ float red[8];
  __shared__ unsigned lrow[16], lslot[16];
  __shared__ int lcount;

  const int b = blockIdx.x, t = threadIdx.x;
  const int lane = t & 63, w = t >> 6;

  if (t == 0) lcount = 0;
  __syncthreads();

  // gather + minmapped init for this block's 16 samples
  if (t < 16) {
    int n = b * 16 + t;
    minmapped[n] = 0xFFFFFFFFu;
    if (labels[n] == 0) {
      unsigned slot = atomicAdd(count, 1u);
      sel[slot] = (unsigned)n;
      int li = atomicAdd(&lcount, 1);
      lrow[li] = (unsigned)n;
      lslot[li] = slot;
    }
  }

  // center row b: convert + constant
  {
    const float* row = cent + (size_t)b * D;
    float4 v = *(const float4*)(row + t * 4);
    *(short4*)(cent_bf + (size_t)b * D + t * 4) =
        make_short4((short)f2bf(v.x), (short)f2bf(v.y), (short)f2bf(v.z),
                    (short)f2bf(v.w));
    float s1 = v.x + v.y + v.z + v.w;
    float s2 = v.x * v.x + v.y * v.y + v.z * v.z + v.w * v.w;
#pragma unroll
    for (int off = 32; off; off >>= 1) {
      s1 += __shfl_down(s1, off);
      s2 += __shfl_down(s2, off);
    }
    if (lane == 0) { red[w] = s1; red[4 + w] = s2; }
    __syncthreads();
    if (t == 0) {
      float a1 = red[0] + red[1] + red[2] + red[3];
      float a2 = red[4] + red[5] + red[6] + red[7];
      cc[b] = a2 - 2.0f * EPS * a1;
    }
  }

  // ff for this block's selected rows (block-cooperative, ~1.6 rows avg)
  const int nl = lcount;
  for (int i = 0; i < nl; ++i) {
    __syncthreads();  // red reuse
    const float* row = feat + (size_t)lrow[i] * D;
    float4 v = *(const float4*)(row + t * 4);
    float s1 = v.x + v.y + v.z + v.w;
    float s2 = v.x * v.x + v.y * v.y + v.z * v.z + v.w * v.w;
#pragma unroll
    for (int off = 32; off; off >>= 1) {
      s1 += __shfl_down(s1, off);
      s2 += __shfl_down(s2, off);
    }
    if (lane == 0) { red[w] = s1; red[4 + w] = s2; }
    __syncthreads();
    if (t == 0) {
      float a1 = red[0] + red[1] + red[2] + red[3];
      float a2 = red[4] + red[5] + red[6] + red[7];
      ff[lslot[i]] = a2 + 2.0f * EPS * a1 + EPS * EPS * (float)D;
    }
  }
}

// ---- k_dist (1024 blocks, grid-stride): minmapped[s] min= (cc[c] - 2*f.c)
// 16 samples x 128 centers per item, 4 waves (wave w owns centers [32w,32w+32)).
// [rows][64] bf16 LDS tiles, 16B-chunk XOR swizzle (j ^= row&7):
// C-tile via global_load_lds (linear dest, inverse-swizzled global source),
// F-tile reg-staged fp32 -> bf16 -> swizzled ds_write.
__global__ __launch_bounds__(TPB) void k_dist(
    const float* __restrict__ feat, const unsigned short* __restrict__ cent_bf,
    const float* __restrict__ cc, const unsigned* __restrict__ count,
    const unsigned* __restrict__ sel, unsigned* __restrict__ minmapped) {
  __shared__ __align__(16) unsigned short Cb[CB * BK];  // 16 KB
  __shared__ __align__(16) unsigned short Fb[SB * BK];  // 2 KB
  __shared__ unsigned rows_s[SB];

  const unsigned cnt = *count;
  const unsigned nwork = ((cnt + SB - 1) / SB) * (C / CB);

  const int t = threadIdx.x;
  const int lane = t & 63, w = t >> 6;

  // F staging geometry: thread t -> sample s = t>>4, k4 = (t&15)*4
  const int fs_ = t >> 4;
  const int fk4 = (t & 15) * 4;
  const int fj = fk4 >> 3, fhalf = (fk4 >> 2) & 1;
  const int foff = fs_ * BK + ((fj ^ (fs_ & 7)) << 3) + (fhalf << 2);
  const int arow = lane & 15, kg = lane >> 4;
  const int c0 = w * 32 + (lane & 15), c1 = c0 + 16;

  for (unsigned wk = blockIdx.x; wk < nwork; wk += DIST_GRID) {
    const unsigned sbase = (wk >> 3) * SB;
    const unsigned cbase = (wk & 7) * CB;

    if (t < SB) rows_s[t] = sel[min(sbase + (unsigned)t, cnt - 1u)];
    __syncthreads();

    const float* fsrc = feat + (size_t)rows_s[fs_] * D + fk4;
    f32x4 acc0 = {0.f, 0.f, 0.f, 0.f}, acc1 = {0.f, 0.f, 0.f, 0.f};

    for (int kt = 0; kt < D / BK; ++kt) {
      const int kbase = kt * BK;
      // C tile: 1024 16B chunks, 4/thread
#pragma unroll
      for (int u = 0; u < 4; ++u) {
        int chunk = (w * 4 + u) * 64 + lane;
        int r = chunk >> 3, j = chunk & 7;
        int jsrc = j ^ (r & 7);
        const unsigned short* src =
            cent_bf + (size_t)(cbase + r) * D + kbase + jsrc * 8;
        GLOAD_LDS16(src, Cb + chunk * 8);
      }
      // F tile: one float4/thread, convert, swizzled ds_write
      {
        float4 v = *(const float4*)(fsrc + kbase);
        *(short4*)(Fb + foff) = make_short4((short)f2bf(v.x), (short)f2bf(v.y),
                                            (short)f2bf(v.z), (short)f2bf(v.w));
      }
      __syncthreads();

#pragma unroll
      for (int ks = 0; ks < 2; ++ks) {
        int jj = (ks << 2) + kg;
        bf16x8 a = *(const bf16x8*)(Fb + arow * BK + ((jj ^ (arow & 7)) << 3));
        bf16x8 b0 = *(const bf16x8*)(Cb + c0 * BK + ((jj ^ (c0 & 7)) << 3));
        bf16x8 b1 = *(const bf16x8*)(Cb + c1 * BK + ((jj ^ (c1 & 7)) << 3));
        acc0 = __builtin_amdgcn_mfma_f32_16x16x32_bf16(a, b0, acc0, 0, 0, 0);
        acc1 = __builtin_amdgcn_mfma_f32_16x16x32_bf16(a, b1, acc1, 0, 0, 0);
      }
      __syncthreads();
    }

    // epilogue: cand = cc[c] - 2*dot; C/D layout: col=lane&15, row=(lane>>4)*4+reg
    float ccv0 = cc[cbase + c0];
    float ccv1 = cc[cbase + c1];
#pragma unroll
    for (int reg = 0; reg < 4; ++reg) {
      float v = fminf(ccv0 - 2.0f * acc0[reg], ccv1 - 2.0f * acc1[reg]);
#pragma unroll
      for (int off = 1; off < 16; off <<= 1) v = fminf(v, __shfl_xor(v, off));
      if ((lane & 15) == 0) {
        unsigned sidx = sbase + (unsigned)((lane >> 4) * 4 + reg);
        if (sidx < cnt) atomicMin(&minmapped[sidx], mapf(v));
      }
    }
    __syncthreads();  // protect rows_s/tiles before next work item
  }
}

// ---- k_final_out (32 blocks): d = sqrt(max(ff + min, 0)); sum; last block
// writes out = sum / (cnt + 1e-5) via done counter.
__global__ __launch_bounds__(TPB) void k_final_out(
    const unsigned* __restrict__ count, const float* __restrict__ ff,
    const unsigned* __restrict__ minmapped, float* __restrict__ num,
    unsigned* __restrict__ done, float* __restrict__ out) {
  const unsigned cnt = *count;
  const int t = threadIdx.x;
  const int lane = t & 63;

  float s = 0.f;
  for (unsigned i = blockIdx.x * TPB + t; i < cnt; i += gridDim.x * TPB) {
    float sq = ff[i] + unmapf(minmapped[i]);
    s += sqrtf(fmaxf(sq, 0.0f));
  }
#pragma unroll
  for (int off = 32; off; off >>= 1) s += __shfl_down(s, off);
  if (lane == 0) atomicAdd(num, s);

  __syncthreads();
  if (t == 0) {
    __threadfence();
    unsigned v = atomicAdd(done, 1u);
    if (v == gridDim.x - 1u) {
      float total = atomicAdd(num, 0.0f);  // coherence-point read
      out[0] = total / ((float)cnt + 1e-5f);
    }
  }
}

extern "C" void kernel_launch(void* const* d_in, const int* in_sizes, int n_in,
                              void* d_out, int out_size, void* d_ws, size_t ws_size,
                              hipStream_t stream) {
  const float* feat = (const float*)d_in[0];
  const int* labels = (const int*)d_in[1];
  const float* cent = (const float*)d_in[2];
  float* out = (float*)d_out;

  char* ws = (char*)d_ws;
  unsigned* count = (unsigned*)ws;                              // @0
  float* num = (float*)(ws + 4);                                // @4
  unsigned* done = (unsigned*)(ws + 8);                         // @8
  unsigned* minmapped = (unsigned*)(ws + 16);                   // N u32
  unsigned* sel = (unsigned*)(ws + 16 + 4 * (size_t)N);         // N u32
  float* cc = (float*)(ws + 16 + 8 * (size_t)N);                // C f32
  float* ff = (float*)(ws + 16 + 8 * (size_t)N + 4 * (size_t)C);  // N f32
  unsigned short* cent_bf =
      (unsigned short*)(ws + 16 + 12 * (size_t)N + 4 * (size_t)C);  // C*D bf16

  hipMemsetAsync(d_ws, 0, 16, stream);

  k_setup<<<1024, TPB, 0, stream>>>(feat, labels, cent, count, sel, minmapped,
                                    cc, ff, cent_bf);
  k_dist<<<DIST_GRID, TPB, 0, stream>>>(feat, cent_bf, cc, count, sel,
                                        minmapped);
  k_final_out<<<32, TPB, 0, stream>>>(count, ff, minmapped, num, done, out);
}